// Round 2
// baseline (120.965 us; speedup 1.0000x reference)
//
#include <hip/hip_runtime.h>

// Problem constants (from reference setup_inputs):
// B=2, K=64, N=16, C=2N=32, Hf=Wf=128, H=W=128
#define B_ 2
#define K_ 64
#define N_ 16
#define C_ 32
#define HF_ 128
#define WF_ 128
#define H_ 128
#define W_ 128
#define HW_ (H_ * W_)                 // 16384
#define PIX_PER_THREAD 4
#define PIX_PER_BLOCK (256 * PIX_PER_THREAD)       // 1024
#define ROWS_PER_BLOCK (PIX_PER_BLOCK / W_)        // 8
#define TILES_PER_BK (HW_ / PIX_PER_BLOCK)         // 16
#define NBLOCKS (B_ * K_ * TILES_PER_BK)           // 2048
#define TOTAL_ELEMS ((double)(B_ * K_ * H_ * W_))  // 2097152
#define LOG2E 1.44269504088896f

// Separable-Gaussian + fused last-block reduction (single heavy kernel).
//   exp(c*(dx^2+dy^2)) = Ex[n][w] * Ey[n][h]
// Ex (16x128, 8 KB) and Ey (16x8) built in LDS once per block; inner loop is
// 1 ds_read_b128 + 4 FMA per gaussian (no transcendentals).
// Epilogue: with e = exp(-g), sig = 1/(1+e), p = m*sig, t = tv*m:
//   bce = log(1+e) - t*log(m) - (1-t)*log(1+e-m)
// (clips never bind: g in (0,16] -> 1-p > 5e-8 >> 1e-12; p-clip folded into lm)
// Final reduction: last-arriving block re-reduces all partials with the exact
// same strided double-precision order as the old reduce_final kernel, so the
// result is bit-identical (absmax stays 0.0).
__global__ __launch_bounds__(256) void gauss_bce_fused(
    const float* __restrict__ centers,  // (B, 32, 128*128)
    const float* __restrict__ radius,   // (B, 1, 128*128)
    const float* __restrict__ mask,     // (B, K)
    const int*   __restrict__ ind,      // (B, K)
    const float* __restrict__ target,   // (B, K, H, W)
    const float* __restrict__ peak,     // (B, K, 2)
    float* __restrict__ partials,       // (NBLOCKS) in workspace
    unsigned int* __restrict__ counter, // 1 uint in workspace (memset to 0)
    float* __restrict__ out)            // 2 floats
{
    __shared__ float sx[N_];
    __shared__ float sy[N_];
    __shared__ float sEx[N_ * W_];                // 8 KB: Ex[n][w]
    __shared__ float sEy[ROWS_PER_BLOCK][N_];     // 512 B: Ey[row][n]
    __shared__ float s_c2;     // -log2(e) / (2 r^2)
    __shared__ float s_m;
    __shared__ float s_lm;     // log(max(m, 1e-12))
    __shared__ float warp_sums[4];
    __shared__ int   s_last;
    __shared__ double dwarp_sums[4];

    const int tid  = threadIdx.x;
    const int bk   = blockIdx.x >> 4;       // / TILES_PER_BK
    const int tile = blockIdx.x & (TILES_PER_BK - 1);
    const int b = bk >> 6;                  // / K_
    const int k = bk & 63;

    // Stage per-(b,k) constants into LDS.
    if (tid < C_) {
        const int ii = ind[b * K_ + k];     // flat index into Hf*Wf
        const float v = centers[(size_t)(b * C_ + tid) * (HF_ * WF_) + ii];
        const int n = tid >> 1;
        if ((tid & 1) == 0) {
            sx[n] = v + peak[(b * K_ + k) * 2 + 0];
        } else {
            sy[n] = v + peak[(b * K_ + k) * 2 + 1];
        }
    } else if (tid == C_) {
        const int ii = ind[b * K_ + k];
        const float r = radius[(size_t)b * (HF_ * WF_) + ii];
        s_c2 = -LOG2E / (2.0f * r * r);
    } else if (tid == C_ + 1) {
        const float mm = mask[b * K_ + k];
        s_m  = mm;
        s_lm = __logf(fmaxf(mm, 1e-12f));
    }
    __syncthreads();

    const float c2 = s_c2;
    const int h0 = tile * ROWS_PER_BLOCK;

    // Build the separable tables. Ex: 8 exp2/thread, coalesced LDS writes.
    #pragma unroll
    for (int i = 0; i < (N_ * W_) / 256; ++i) {   // 8 iterations
        const int idx = tid + i * 256;
        const float dx = sx[idx >> 7] - (float)(idx & (W_ - 1));
        sEx[idx] = exp2f(c2 * dx * dx);
    }
    if (tid < N_ * ROWS_PER_BLOCK) {              // 128 threads
        const int n = tid & (N_ - 1);
        const int r = tid >> 4;
        const float dy = sy[n] - (float)(h0 + r);
        sEy[r][n] = exp2f(c2 * dy * dy);
    }
    __syncthreads();

    const int row = tid >> 5;              // 0..7
    const int w0  = (tid & 31) << 2;       // multiple of 4
    const int h   = h0 + row;
    const float m  = s_m;
    const float lm = s_lm;

    // Vectorized target load (coalesced, 16 B/lane).
    const float4 t4 = *(const float4*)&target[((size_t)(b * K_ + k) * H_ + h) * W_ + w0];

    // Y-factors for this thread's row (broadcast LDS reads).
    float ey[N_];
    #pragma unroll
    for (int q = 0; q < N_ / 4; ++q) {
        const float4 e4 = *(const float4*)&sEy[row][q * 4];
        ey[q * 4 + 0] = e4.x; ey[q * 4 + 1] = e4.y;
        ey[q * 4 + 2] = e4.z; ey[q * 4 + 3] = e4.w;
    }

    // Main loop: 16 x (ds_read_b128 + 4 FMA). Conflict-free: lanes 0..31 read
    // consecutive 16B chunks of one Ex row; lanes 32..63 read the same
    // addresses (broadcast).
    float gx = 0.0f, gy = 0.0f, gz = 0.0f, gw = 0.0f;
    #pragma unroll
    for (int n = 0; n < N_; ++n) {
        const float4 x4 = *(const float4*)&sEx[n * W_ + w0];
        const float e = ey[n];
        gx = __builtin_fmaf(x4.x, e, gx);
        gy = __builtin_fmaf(x4.y, e, gy);
        gz = __builtin_fmaf(x4.z, e, gz);
        gw = __builtin_fmaf(x4.w, e, gw);
    }

    const float gs[4] = {gx, gy, gz, gw};
    const float tv[4] = {t4.x, t4.y, t4.z, t4.w};
    float acc = 0.0f;
    #pragma unroll
    for (int j = 0; j < PIX_PER_THREAD; ++j) {
        const float e  = __expf(-gs[j]);
        const float L1 = __logf(1.0f + e);
        const float L2 = __logf(fmaxf(1.0f + e - m, 1e-12f));
        const float t  = tv[j] * m;
        acc += (L1 - L2) + t * (L2 - lm);
    }

    // Block reduction: wave64 shuffle, then LDS across the 4 waves.
    float v = acc;
    #pragma unroll
    for (int off = 32; off > 0; off >>= 1)
        v += __shfl_down(v, off, 64);
    const int lane = tid & 63;
    const int wid  = tid >> 6;
    if (lane == 0) warp_sums[wid] = v;
    __syncthreads();

    // Publish this block's partial; last-arriving block does the final sum.
    if (tid == 0) {
        partials[blockIdx.x] = warp_sums[0] + warp_sums[1] + warp_sums[2] + warp_sums[3];
        __threadfence();                          // make partial device-visible
        const unsigned int old = atomicAdd(counter, 1u);
        s_last = (old == (unsigned int)(NBLOCKS - 1)) ? 1 : 0;
    }
    __syncthreads();
    if (!s_last) return;
    __threadfence();                              // acquire side

    // Final reduction — identical order to the old reduce_final kernel
    // (strided double accumulate + wave shuffle), so bit-identical output.
    const volatile float* __restrict__ vp = partials;
    double dacc = 0.0;
    #pragma unroll
    for (int i = 0; i < NBLOCKS / 256; ++i)
        dacc += (double)vp[i * 256 + tid];

    #pragma unroll
    for (int off = 32; off > 0; off >>= 1)
        dacc += __shfl_down(dacc, off, 64);
    if (lane == 0) dwarp_sums[wid] = dacc;
    __syncthreads();
    if (tid == 0) {
        const double s = dwarp_sums[0] + dwarp_sums[1] + dwarp_sums[2] + dwarp_sums[3];
        const float loss = (float)(s / TOTAL_ELEMS);
        out[0] = loss;
        out[1] = loss;
    }
}

extern "C" void kernel_launch(void* const* d_in, const int* in_sizes, int n_in,
                              void* d_out, int out_size, void* d_ws, size_t ws_size,
                              hipStream_t stream) {
    const float* centers = (const float*)d_in[0];
    const float* radius  = (const float*)d_in[1];
    const float* mask    = (const float*)d_in[2];
    const int*   ind     = (const int*)d_in[3];
    const float* target  = (const float*)d_in[4];
    const float* peak    = (const float*)d_in[5];
    float* out = (float*)d_out;
    float* partials = (float*)d_ws;                       // NBLOCKS floats = 8 KB
    unsigned int* counter = (unsigned int*)((char*)d_ws + NBLOCKS * sizeof(float));

    hipMemsetAsync(counter, 0, sizeof(unsigned int), stream);
    gauss_bce_fused<<<NBLOCKS, 256, 0, stream>>>(
        centers, radius, mask, ind, target, peak, partials, counter, out);
}

// Round 3
// 95.559 us; speedup vs baseline: 1.2659x; 1.2659x over previous
//
#include <hip/hip_runtime.h>

// Problem constants (from reference setup_inputs):
// B=2, K=64, N=16, C=2N=32, Hf=Wf=128, H=W=128
#define B_ 2
#define K_ 64
#define N_ 16
#define C_ 32
#define HF_ 128
#define WF_ 128
#define H_ 128
#define W_ 128
#define HW_ (H_ * W_)                 // 16384
#define PIX_PER_THREAD 4
#define PIX_PER_BLOCK (256 * PIX_PER_THREAD)       // 1024
#define ROWS_PER_BLOCK (PIX_PER_BLOCK / W_)        // 8
#define TILES_PER_BK (HW_ / PIX_PER_BLOCK)         // 16
#define NBLOCKS (B_ * K_ * TILES_PER_BK)           // 2048
#define TOTAL_ELEMS ((double)(B_ * K_ * H_ * W_))  // 2097152
#define LOG2E 1.44269504088896f

// Separable-Gaussian + fused last-block reduction, FENCE-FREE.
// Round-2 lesson: __threadfence() (agent release) emits buffer_wbl2; with the
// 256-MiB poison fill's dirty lines in L2, 2048 per-block writeback walks
// serialized the kernel (57-65 us, VALUBusy 7%). This version uses only
// memory-side-coherent operations:
//   - partial published with a RELAXED agent-scope atomic store (sc1
//     write-through, no cache maintenance),
//   - explicit s_waitcnt vmcnt(0) so the store is ACKED at the coherent
//     point before the arrival-counter atomic is issued (ordering by
//     completion, not by fence),
//   - arrival counter is a module __device__ global (persists across
//     launches; 2048 | 2^32 so wraparound is seamless; no memset node),
//   - last block reads partials with relaxed agent-scope atomic loads
//     (bypass L1/L2) in the EXACT strided double order of the old
//     reduce_final kernel -> bit-identical result, absmax 0.0.
__device__ unsigned int g_arrivals;   // .bss, zero at module load

__global__ __launch_bounds__(256) void gauss_bce_fused(
    const float* __restrict__ centers,  // (B, 32, 128*128)
    const float* __restrict__ radius,   // (B, 1, 128*128)
    const float* __restrict__ mask,     // (B, K)
    const int*   __restrict__ ind,      // (B, K)
    const float* __restrict__ target,   // (B, K, H, W)
    const float* __restrict__ peak,     // (B, K, 2)
    float* __restrict__ partials,       // (NBLOCKS) in workspace
    float* __restrict__ out)            // 2 floats
{
    __shared__ float sx[N_];
    __shared__ float sy[N_];
    __shared__ float sEx[N_ * W_];                // 8 KB: Ex[n][w]
    __shared__ float sEy[ROWS_PER_BLOCK][N_];     // 512 B: Ey[row][n]
    __shared__ float s_c2;     // -log2(e) / (2 r^2)
    __shared__ float s_m;
    __shared__ float s_lm;     // log(max(m, 1e-12))
    __shared__ float warp_sums[4];
    __shared__ int   s_last;
    __shared__ double dwarp_sums[4];

    const int tid  = threadIdx.x;
    const int bk   = blockIdx.x >> 4;       // / TILES_PER_BK
    const int tile = blockIdx.x & (TILES_PER_BK - 1);
    const int b = bk >> 6;                  // / K_
    const int k = bk & 63;

    // Stage per-(b,k) constants into LDS.
    if (tid < C_) {
        const int ii = ind[b * K_ + k];     // flat index into Hf*Wf
        const float v = centers[(size_t)(b * C_ + tid) * (HF_ * WF_) + ii];
        const int n = tid >> 1;
        if ((tid & 1) == 0) {
            sx[n] = v + peak[(b * K_ + k) * 2 + 0];
        } else {
            sy[n] = v + peak[(b * K_ + k) * 2 + 1];
        }
    } else if (tid == C_) {
        const int ii = ind[b * K_ + k];
        const float r = radius[(size_t)b * (HF_ * WF_) + ii];
        s_c2 = -LOG2E / (2.0f * r * r);
    } else if (tid == C_ + 1) {
        const float mm = mask[b * K_ + k];
        s_m  = mm;
        s_lm = __logf(fmaxf(mm, 1e-12f));
    }
    __syncthreads();

    const float c2 = s_c2;
    const int h0 = tile * ROWS_PER_BLOCK;

    // Build the separable tables. Ex: 8 exp2/thread, coalesced LDS writes.
    #pragma unroll
    for (int i = 0; i < (N_ * W_) / 256; ++i) {   // 8 iterations
        const int idx = tid + i * 256;
        const float dx = sx[idx >> 7] - (float)(idx & (W_ - 1));
        sEx[idx] = exp2f(c2 * dx * dx);
    }
    if (tid < N_ * ROWS_PER_BLOCK) {              // 128 threads
        const int n = tid & (N_ - 1);
        const int r = tid >> 4;
        const float dy = sy[n] - (float)(h0 + r);
        sEy[r][n] = exp2f(c2 * dy * dy);
    }
    __syncthreads();

    const int row = tid >> 5;              // 0..7
    const int w0  = (tid & 31) << 2;       // multiple of 4
    const int h   = h0 + row;
    const float m  = s_m;
    const float lm = s_lm;

    // Vectorized target load (coalesced, 16 B/lane).
    const float4 t4 = *(const float4*)&target[((size_t)(b * K_ + k) * H_ + h) * W_ + w0];

    // Y-factors for this thread's row (broadcast LDS reads).
    float ey[N_];
    #pragma unroll
    for (int q = 0; q < N_ / 4; ++q) {
        const float4 e4 = *(const float4*)&sEy[row][q * 4];
        ey[q * 4 + 0] = e4.x; ey[q * 4 + 1] = e4.y;
        ey[q * 4 + 2] = e4.z; ey[q * 4 + 3] = e4.w;
    }

    // Main loop: 16 x (ds_read_b128 + 4 FMA). Conflict-free: lanes 0..31 read
    // consecutive 16B chunks of one Ex row; lanes 32..63 read the same
    // addresses (broadcast).
    float gx = 0.0f, gy = 0.0f, gz = 0.0f, gw = 0.0f;
    #pragma unroll
    for (int n = 0; n < N_; ++n) {
        const float4 x4 = *(const float4*)&sEx[n * W_ + w0];
        const float e = ey[n];
        gx = __builtin_fmaf(x4.x, e, gx);
        gy = __builtin_fmaf(x4.y, e, gy);
        gz = __builtin_fmaf(x4.z, e, gz);
        gw = __builtin_fmaf(x4.w, e, gw);
    }

    const float gs[4] = {gx, gy, gz, gw};
    const float tv[4] = {t4.x, t4.y, t4.z, t4.w};
    float acc = 0.0f;
    #pragma unroll
    for (int j = 0; j < PIX_PER_THREAD; ++j) {
        const float e  = __expf(-gs[j]);
        const float L1 = __logf(1.0f + e);
        const float L2 = __logf(fmaxf(1.0f + e - m, 1e-12f));
        const float t  = tv[j] * m;
        acc += (L1 - L2) + t * (L2 - lm);
    }

    // Block reduction: wave64 shuffle, then LDS across the 4 waves.
    float v = acc;
    #pragma unroll
    for (int off = 32; off > 0; off >>= 1)
        v += __shfl_down(v, off, 64);
    const int lane = tid & 63;
    const int wid  = tid >> 6;
    if (lane == 0) warp_sums[wid] = v;
    __syncthreads();

    // Publish this block's partial (no fences anywhere).
    if (tid == 0) {
        const float partial = warp_sums[0] + warp_sums[1] + warp_sums[2] + warp_sums[3];
        // Relaxed agent-scope store: sc1 write-through to the coherent point.
        __hip_atomic_store(&partials[blockIdx.x], partial,
                           __ATOMIC_RELAXED, __HIP_MEMORY_SCOPE_AGENT);
        // Ensure the store is ACKED before the counter add is issued.
        asm volatile("s_waitcnt vmcnt(0)" ::: "memory");
        const unsigned int old = __hip_atomic_fetch_add(&g_arrivals, 1u,
                                   __ATOMIC_RELAXED, __HIP_MEMORY_SCOPE_AGENT);
        // 2048 divides 2^32: wraparound seamless, no reset ever needed.
        s_last = ((old & (unsigned int)(NBLOCKS - 1)) == (unsigned int)(NBLOCKS - 1)) ? 1 : 0;
    }
    __syncthreads();
    if (!s_last) return;

    // Final reduction — identical order to the old reduce_final kernel
    // (strided double accumulate + wave shuffle), so bit-identical output.
    // Relaxed agent-scope atomic loads bypass (possibly stale) L1/L2.
    double dacc = 0.0;
    #pragma unroll
    for (int i = 0; i < NBLOCKS / 256; ++i) {
        const float p = __hip_atomic_load(&partials[i * 256 + tid],
                          __ATOMIC_RELAXED, __HIP_MEMORY_SCOPE_AGENT);
        dacc += (double)p;
    }

    #pragma unroll
    for (int off = 32; off > 0; off >>= 1)
        dacc += __shfl_down(dacc, off, 64);
    if (lane == 0) dwarp_sums[wid] = dacc;
    __syncthreads();
    if (tid == 0) {
        const double s = dwarp_sums[0] + dwarp_sums[1] + dwarp_sums[2] + dwarp_sums[3];
        const float loss = (float)(s / TOTAL_ELEMS);
        out[0] = loss;
        out[1] = loss;
    }
}

extern "C" void kernel_launch(void* const* d_in, const int* in_sizes, int n_in,
                              void* d_out, int out_size, void* d_ws, size_t ws_size,
                              hipStream_t stream) {
    const float* centers = (const float*)d_in[0];
    const float* radius  = (const float*)d_in[1];
    const float* mask    = (const float*)d_in[2];
    const int*   ind     = (const int*)d_in[3];
    const float* target  = (const float*)d_in[4];
    const float* peak    = (const float*)d_in[5];
    float* out = (float*)d_out;
    float* partials = (float*)d_ws;   // NBLOCKS floats = 8 KB

    gauss_bce_fused<<<NBLOCKS, 256, 0, stream>>>(
        centers, radius, mask, ind, target, peak, partials, out);
}

// Round 4
// 72.817 us; speedup vs baseline: 1.6612x; 1.3123x over previous
//
#include <hip/hip_runtime.h>

// Problem constants (from reference setup_inputs):
// B=2, K=64, N=16, C=2N=32, Hf=Wf=128, H=W=128
#define B_ 2
#define K_ 64
#define N_ 16
#define C_ 32
#define HF_ 128
#define WF_ 128
#define H_ 128
#define W_ 128
#define HW_ (H_ * W_)                 // 16384
#define PIX_PER_THREAD 8
#define PIX_PER_BLOCK (256 * PIX_PER_THREAD)       // 2048
#define ROWS_PER_BLOCK (PIX_PER_BLOCK / W_)        // 16
#define TILES_PER_BK (HW_ / PIX_PER_BLOCK)         // 8
#define NBLOCKS (B_ * K_ * TILES_PER_BK)           // 1024
#define TOTAL_ELEMS ((double)(B_ * K_ * H_ * W_))  // 2097152
#define LOG2E 1.44269504088896f

// Two-kernel separable-Gaussian version (round-3 lesson: ANY cross-block
// sync — threadfence/wbl2 OR same-address device-scope atomics — costs
// 20-60 us exposed tail on this 8-XCD part, far more than the ~2-4 us
// dispatch gap it saves. Keep the tiny second kernel.)
//
//   exp(c*(dx^2+dy^2)) = Ex[n][w] * Ey[n][h]
// Ex (16x128, 8 KB) and Ey (16x16) built in LDS once per block.
// Each thread owns 2 rows x 4 cols (rows r and r+8), so each ds_read_b128
// of Ex feeds 8 FMAs (per-pixel LDS traffic halved vs PIX_PER_THREAD=4),
// and 1024 blocks (vs 2048) halve the total table-build exp2 work.
// Epilogue: with e = exp(-g), sig = 1/(1+e), p = m*sig, t = tv*m:
//   bce = log(1+e) - t*log(m) - (1-t)*log(1+e-m)
// (clips never bind: g in (0,16] -> 1-p > 5e-8 >> 1e-12; p-clip folded into lm)
__global__ __launch_bounds__(256) void gauss_bce_partial(
    const float* __restrict__ centers,  // (B, 32, 128*128)
    const float* __restrict__ radius,   // (B, 1, 128*128)
    const float* __restrict__ mask,     // (B, K)
    const int*   __restrict__ ind,      // (B, K)
    const float* __restrict__ target,   // (B, K, H, W)
    const float* __restrict__ peak,     // (B, K, 2)
    float* __restrict__ partials)       // (NBLOCKS)
{
    __shared__ float sx[N_];
    __shared__ float sy[N_];
    __shared__ float sEx[N_ * W_];                // 8 KB: Ex[n][w]
    __shared__ float sEy[ROWS_PER_BLOCK][N_];     // 1 KB: Ey[row][n]
    __shared__ float s_c2;     // -log2(e) / (2 r^2)
    __shared__ float s_m;
    __shared__ float s_lm;     // log(max(m, 1e-12))
    __shared__ float warp_sums[4];

    const int tid  = threadIdx.x;
    const int bk   = blockIdx.x >> 3;       // / TILES_PER_BK
    const int tile = blockIdx.x & (TILES_PER_BK - 1);
    const int b = bk >> 6;                  // / K_
    const int k = bk & 63;

    // Stage per-(b,k) constants into LDS.
    if (tid < C_) {
        const int ii = ind[b * K_ + k];     // flat index into Hf*Wf
        const float v = centers[(size_t)(b * C_ + tid) * (HF_ * WF_) + ii];
        const int n = tid >> 1;
        if ((tid & 1) == 0) {
            sx[n] = v + peak[(b * K_ + k) * 2 + 0];
        } else {
            sy[n] = v + peak[(b * K_ + k) * 2 + 1];
        }
    } else if (tid == C_) {
        const int ii = ind[b * K_ + k];
        const float r = radius[(size_t)b * (HF_ * WF_) + ii];
        s_c2 = -LOG2E / (2.0f * r * r);
    } else if (tid == C_ + 1) {
        const float mm = mask[b * K_ + k];
        s_m  = mm;
        s_lm = __logf(fmaxf(mm, 1e-12f));
    }
    __syncthreads();

    const float c2 = s_c2;
    const int h0 = tile * ROWS_PER_BLOCK;

    // Build the separable tables.
    // Ex: 8 exp2/thread, coalesced LDS writes.
    #pragma unroll
    for (int i = 0; i < (N_ * W_) / 256; ++i) {   // 8 iterations
        const int idx = tid + i * 256;
        const float dx = sx[idx >> 7] - (float)(idx & (W_ - 1));
        sEx[idx] = exp2f(c2 * dx * dx);
    }
    // Ey: 16 rows x 16 gaussians = 256 -> exactly 1 exp2/thread, no branch.
    {
        const int n = tid & (N_ - 1);
        const int r = tid >> 4;
        const float dy = sy[n] - (float)(h0 + r);
        sEy[r][n] = exp2f(c2 * dy * dy);
    }
    __syncthreads();

    const int rA = tid >> 5;               // 0..7
    const int rB = rA + 8;                 // 8..15
    const int w0 = (tid & 31) << 2;        // multiple of 4
    const float m  = s_m;
    const float lm = s_lm;

    // Vectorized target loads (coalesced: half-wave contiguous 512B rows).
    const size_t rowbase = (size_t)(b * K_ + k) * H_;
    const float4 t4A = *(const float4*)&target[(rowbase + h0 + rA) * W_ + w0];
    const float4 t4B = *(const float4*)&target[(rowbase + h0 + rB) * W_ + w0];

    // Y-factors for this thread's two rows (broadcast LDS reads).
    float eyA[N_], eyB[N_];
    #pragma unroll
    for (int q = 0; q < N_ / 4; ++q) {
        const float4 a4 = *(const float4*)&sEy[rA][q * 4];
        const float4 b4 = *(const float4*)&sEy[rB][q * 4];
        eyA[q * 4 + 0] = a4.x; eyA[q * 4 + 1] = a4.y;
        eyA[q * 4 + 2] = a4.z; eyA[q * 4 + 3] = a4.w;
        eyB[q * 4 + 0] = b4.x; eyB[q * 4 + 1] = b4.y;
        eyB[q * 4 + 2] = b4.z; eyB[q * 4 + 3] = b4.w;
    }

    // Main loop: 16 x (1 ds_read_b128 + 8 FMA). Conflict-free: lanes 0..31
    // read consecutive 16B chunks of one Ex row (2-way aliasing = free);
    // lanes 32..63 broadcast the same addresses.
    float gAx = 0.f, gAy = 0.f, gAz = 0.f, gAw = 0.f;
    float gBx = 0.f, gBy = 0.f, gBz = 0.f, gBw = 0.f;
    #pragma unroll
    for (int n = 0; n < N_; ++n) {
        const float4 x4 = *(const float4*)&sEx[n * W_ + w0];
        const float ea = eyA[n];
        const float eb = eyB[n];
        gAx = __builtin_fmaf(x4.x, ea, gAx);
        gAy = __builtin_fmaf(x4.y, ea, gAy);
        gAz = __builtin_fmaf(x4.z, ea, gAz);
        gAw = __builtin_fmaf(x4.w, ea, gAw);
        gBx = __builtin_fmaf(x4.x, eb, gBx);
        gBy = __builtin_fmaf(x4.y, eb, gBy);
        gBz = __builtin_fmaf(x4.z, eb, gBz);
        gBw = __builtin_fmaf(x4.w, eb, gBw);
    }

    const float gs[PIX_PER_THREAD] = {gAx, gAy, gAz, gAw, gBx, gBy, gBz, gBw};
    const float tv[PIX_PER_THREAD] = {t4A.x, t4A.y, t4A.z, t4A.w,
                                      t4B.x, t4B.y, t4B.z, t4B.w};
    float acc = 0.0f;
    #pragma unroll
    for (int j = 0; j < PIX_PER_THREAD; ++j) {
        const float e  = __expf(-gs[j]);
        const float L1 = __logf(1.0f + e);
        const float L2 = __logf(fmaxf(1.0f + e - m, 1e-12f));
        const float t  = tv[j] * m;
        acc += (L1 - L2) + t * (L2 - lm);
    }

    // Block reduction: wave64 shuffle, then LDS across the 4 waves.
    float v = acc;
    #pragma unroll
    for (int off = 32; off > 0; off >>= 1)
        v += __shfl_down(v, off, 64);
    const int lane = tid & 63;
    const int wid  = tid >> 6;
    if (lane == 0) warp_sums[wid] = v;
    __syncthreads();
    if (tid == 0) {
        partials[blockIdx.x] = warp_sums[0] + warp_sums[1] + warp_sums[2] + warp_sums[3];
    }
}

__global__ __launch_bounds__(256) void reduce_final(
    const float* __restrict__ partials, float* __restrict__ out)
{
    __shared__ double warp_sums[4];
    const int tid = threadIdx.x;
    double acc = 0.0;
    #pragma unroll
    for (int i = 0; i < NBLOCKS / 256; ++i)       // 4 iterations
        acc += (double)partials[i * 256 + tid];

    #pragma unroll
    for (int off = 32; off > 0; off >>= 1)
        acc += __shfl_down(acc, off, 64);
    const int lane = tid & 63;
    const int wid  = tid >> 6;
    if (lane == 0) warp_sums[wid] = acc;
    __syncthreads();
    if (tid == 0) {
        double s = warp_sums[0] + warp_sums[1] + warp_sums[2] + warp_sums[3];
        float loss = (float)(s / TOTAL_ELEMS);
        out[0] = loss;
        out[1] = loss;
    }
}

extern "C" void kernel_launch(void* const* d_in, const int* in_sizes, int n_in,
                              void* d_out, int out_size, void* d_ws, size_t ws_size,
                              hipStream_t stream) {
    const float* centers = (const float*)d_in[0];
    const float* radius  = (const float*)d_in[1];
    const float* mask    = (const float*)d_in[2];
    const int*   ind     = (const int*)d_in[3];
    const float* target  = (const float*)d_in[4];
    const float* peak    = (const float*)d_in[5];
    float* out = (float*)d_out;
    float* partials = (float*)d_ws;   // NBLOCKS floats = 4 KB

    gauss_bce_partial<<<NBLOCKS, 256, 0, stream>>>(
        centers, radius, mask, ind, target, peak, partials);
    reduce_final<<<1, 256, 0, stream>>>(partials, out);
}